// Round 8
// baseline (243.541 us; speedup 1.0000x reference)
//
#include <hip/hip_runtime.h>
#include <stdint.h>
#include <stddef.h>

#define H 512
#define XD 256
#define NCHLD 32768
#define NB 32               // children per k2 block
#define MROWS 256           // h-rows per k2 block (M-split 2)
#define NSHARD 32

// ws layout (floats):
#define WS_PREF 0           // [0,512)       pre_f = w_f@x + b_f
#define WS_IOU  512         // [512,2048)    iou logits
#define WS_CACC 2048        // [2048,18432)  32 shards x 512
#define WS_HSUM 18432       // [18432,34816) 32 shards x 512
#define WS_UF16 34816       // u_f as f16: 262144 halves = 131072 float slots

typedef float f32x4 __attribute__((ext_vector_type(4)));
typedef _Float16 f16x8 __attribute__((ext_vector_type(8)));

__device__ __forceinline__ float sigm(float x) { return 1.0f / (1.0f + __expf(-x)); }

// k0: (a) u_f -> f16 (blocks 0..255); (b) pre_f + zero shard arrays (blocks 256..263).
__global__ __launch_bounds__(256) void k0_setup(const float* __restrict__ x,
                                                const float* __restrict__ w_f,
                                                const float* __restrict__ b_f,
                                                const float* __restrict__ u_f,
                                                float* __restrict__ ws) {
    const int b = blockIdx.x;
    if (b < 256) {
        const int i = (b * 256 + threadIdx.x) * 4;
        float4 v = *(const float4*)(u_f + i);
        _Float16 h0 = (_Float16)v.x, h1 = (_Float16)v.y;
        _Float16 h2 = (_Float16)v.z, h3 = (_Float16)v.w;
        _Float16* dst = (_Float16*)(ws + WS_UF16) + i;
        dst[0] = h0; dst[1] = h1; dst[2] = h2; dst[3] = h3;
    } else {
        const int gid = (b - 256) * 256 + threadIdx.x;   // [0,2048)
        const int row = gid >> 2;
        const int part = gid & 3;
        const float4* wr = (const float4*)(w_f + (size_t)row * XD) + part * 16;
        const float4* xv = (const float4*)x + part * 16;
        float acc = 0.0f;
#pragma unroll 4
        for (int i = 0; i < 16; ++i) {
            float4 a = wr[i], c = xv[i];
            acc += a.x * c.x + a.y * c.y + a.z * c.z + a.w * c.w;
        }
        acc += __shfl_xor(acc, 1);
        acc += __shfl_xor(acc, 2);
        if (part == 0) ws[WS_PREF + row] = acc + b_f[row];
        // zero CACC+HSUM = floats [2048, 34816) = float4 idx [512, 8704)
        float4 z = make_float4(0.f, 0.f, 0.f, 0.f);
#pragma unroll
        for (int t = 0; t < 4; ++t)
            ((float4*)ws)[512 + gid * 4 + t] = z;
    }
}

// k2: fs = sigmoid(pre_f + u_f@hs^T) fused with c partials and h_sum partials.
// 256-thr blocks (4 waves), NB=32 children x MROWS=256 rows, grid 2048 ->
// 4 blocks/CU (LDS 35 KB, regs <=128 total): cross-block phase mixing.
__global__ __launch_bounds__(256, 4) void k2_main(const float* __restrict__ hs,
                                                  const float* __restrict__ cs,
                                                  float* __restrict__ ws) {
    __shared__ _Float16 Bs[NB * H];   // 32 KB, slot-swizzled
    __shared__ float hsum_l[H];       // 2 KB

    const _Float16* uf16 = (const _Float16*)(ws + WS_UF16);
    const float* pre_f = ws + WS_PREF;
    const int bid   = blockIdx.x;
    const int ntile = bid >> 1;
    const int mtile = bid & 1;
    const int c0    = ntile * NB;
    const int r0    = mtile * MROWS;
    float* c_acc = ws + WS_CACC + (bid & (NSHARD - 1)) * H;

    const int tid  = threadIdx.x;
    const int wid  = tid >> 6;
    const int lane = tid & 63;
    const int fc   = lane & 15;
    const int q    = lane >> 4;

    hsum_l[tid] = 0.0f;
    hsum_l[tid + 256] = 0.0f;
    __syncthreads();

    // ---- stage: wave wid -> children [wid*8,+8), lane -> dims [lane*8,+8) ----
    // LDS slot-swizzle: dim-group g stored at slot (g ^ (child&7)); child&7 == j here.
    {
        const float* g0 = hs + (size_t)(c0 + wid * 8) * H + lane * 8;
        _Float16* wbase = Bs + (size_t)(wid * 8) * H + ((lane ^ 0) * 0);  // base; per-j below
        float4 ha = make_float4(0.f, 0.f, 0.f, 0.f);
        float4 hb = make_float4(0.f, 0.f, 0.f, 0.f);
#pragma unroll
        for (int half = 0; half < 2; ++half) {   // 2 batches of 4 children
            float4 ra[4], rb[4];
#pragma unroll
            for (int j = 0; j < 4; ++j) {
                const int cj = half * 4 + j;
                ra[j] = *(const float4*)(g0 + (size_t)cj * H);
                rb[j] = *(const float4*)(g0 + (size_t)cj * H + 4);
            }
#pragma unroll
            for (int j = 0; j < 4; ++j) {
                const int cj = half * 4 + j;
                f16x8 hv;
                hv[0] = (_Float16)ra[j].x; hv[1] = (_Float16)ra[j].y;
                hv[2] = (_Float16)ra[j].z; hv[3] = (_Float16)ra[j].w;
                hv[4] = (_Float16)rb[j].x; hv[5] = (_Float16)rb[j].y;
                hv[6] = (_Float16)rb[j].z; hv[7] = (_Float16)rb[j].w;
                *(f16x8*)(Bs + (size_t)(wid * 8 + cj) * H + ((lane ^ cj) << 3)) = hv;
                ha.x += ra[j].x; ha.y += ra[j].y; ha.z += ra[j].z; ha.w += ra[j].w;
                hb.x += rb[j].x; hb.y += rb[j].y; hb.z += rb[j].z; hb.w += rb[j].w;
            }
        }
        if (mtile == 0) {   // h_sum partial: lane owns dims [lane*8, +8)
            float* hd = &hsum_l[lane * 8];
            atomicAdd(hd + 0, ha.x); atomicAdd(hd + 1, ha.y);
            atomicAdd(hd + 2, ha.z); atomicAdd(hd + 3, ha.w);
            atomicAdd(hd + 4, hb.x); atomicAdd(hd + 5, hb.y);
            atomicAdd(hd + 6, hb.z); atomicAdd(hd + 7, hb.w);
        }
    }
    __syncthreads();

    if (mtile == 0) {   // flush block-partial h_sum (fire-and-forget, overlaps K-loop)
        float* shard = ws + WS_HSUM + (ntile & (NSHARD - 1)) * H;
        atomicAdd(&shard[tid], hsum_l[tid]);
        atomicAdd(&shard[tid + 256], hsum_l[tid + 256]);
    }

    // ---- barrier-free K-loop: wave owns rows [r0+wid*64, +64), 2 col-tiles ----
    f32x4 acc[4][2];
    const f32x4 vzero = {0.0f, 0.0f, 0.0f, 0.0f};
#pragma unroll
    for (int rt = 0; rt < 4; ++rt) {
        acc[rt][0] = vzero;
        acc[rt][1] = vzero;
    }

    const _Float16* abase = uf16 + (size_t)(r0 + wid * 64 + fc) * H + q * 8;

#pragma unroll
    for (int kk = 0; kk < 16; ++kk) {
        f16x8 af[4];
#pragma unroll
        for (int rt = 0; rt < 4; ++rt)
            af[rt] = *(const f16x8*)(abase + (size_t)rt * 16 * H + kk * 32);
        f16x8 bf[2];
#pragma unroll
        for (int ct = 0; ct < 2; ++ct)
            bf[ct] = *(const f16x8*)(Bs + (size_t)(ct * 16 + fc) * H + (((kk * 4 + q) ^ (fc & 7)) << 3));
#pragma unroll
        for (int ct = 0; ct < 2; ++ct)
#pragma unroll
            for (int rt = 0; rt < 4; ++rt)
                acc[rt][ct] = __builtin_amdgcn_mfma_f32_16x16x32_f16(af[rt], bf[ct], acc[rt][ct], 0, 0, 0);
    }

    // ---- epilogue: sigmoid, * cs, reduce over 16 children per col-tile ----
#pragma unroll
    for (int rt = 0; rt < 4; ++rt) {
        const int rglob = r0 + wid * 64 + rt * 16 + q * 4;
        float4 pf = *(const float4*)(pre_f + rglob);
        f32x4 csum = vzero;
#pragma unroll
        for (int ct = 0; ct < 2; ++ct) {
            const int child = c0 + ct * 16 + fc;
            float4 cv = *(const float4*)(cs + (size_t)child * H + rglob);
            csum[0] += sigm(acc[rt][ct][0] + pf.x) * cv.x;
            csum[1] += sigm(acc[rt][ct][1] + pf.y) * cv.y;
            csum[2] += sigm(acc[rt][ct][2] + pf.z) * cv.z;
            csum[3] += sigm(acc[rt][ct][3] + pf.w) * cv.w;
        }
#pragma unroll
        for (int m = 1; m <= 8; m <<= 1) {
            csum[0] += __shfl_xor(csum[0], m); csum[1] += __shfl_xor(csum[1], m);
            csum[2] += __shfl_xor(csum[2], m); csum[3] += __shfl_xor(csum[3], m);
        }
        if (fc == 0) {
            atomicAdd(&c_acc[rglob + 0], csum[0]); atomicAdd(&c_acc[rglob + 1], csum[1]);
            atomicAdd(&c_acc[rglob + 2], csum[2]); atomicAdd(&c_acc[rglob + 3], csum[3]);
        }
    }
}

// k3: iou logits; reduces the 32 h_sum shards into LDS first. 96 blocks x 256 thr.
__global__ __launch_bounds__(256) void k3_iou(const float* __restrict__ x,
                                              const float* __restrict__ w_iou,
                                              const float* __restrict__ u_iou,
                                              const float* __restrict__ b_iou,
                                              float* __restrict__ ws) {
    __shared__ float h_red[H];
    const int tid = threadIdx.x;
    {
        float a0 = 0.0f, a1 = 0.0f;
#pragma unroll 8
        for (int s = 0; s < NSHARD; ++s) {
            a0 += ws[WS_HSUM + s * H + tid * 2 + 0];
            a1 += ws[WS_HSUM + s * H + tid * 2 + 1];
        }
        h_red[tid * 2 + 0] = a0;
        h_red[tid * 2 + 1] = a1;
    }
    __syncthreads();

    const int gid = blockIdx.x * 256 + tid;   // [0,24576)
    const int row = gid >> 4;                  // [0,1536)
    const int part = gid & 15;
    float acc = 0.0f;
    const float4* wr = (const float4*)(w_iou + (size_t)row * XD) + part * 4;
    const float4* xv = (const float4*)x + part * 4;
#pragma unroll
    for (int i = 0; i < 4; ++i) {
        float4 a = wr[i], b = xv[i];
        acc += a.x * b.x + a.y * b.y + a.z * b.z + a.w * b.w;
    }
    const float4* ur = (const float4*)(u_iou + (size_t)row * H) + part * 8;
    const float4* hv = (const float4*)h_red + part * 8;
#pragma unroll
    for (int i = 0; i < 8; ++i) {
        float4 a = ur[i], b = hv[i];
        acc += a.x * b.x + a.y * b.y + a.z * b.z + a.w * b.w;
    }
    acc += __shfl_xor(acc, 1);
    acc += __shfl_xor(acc, 2);
    acc += __shfl_xor(acc, 4);
    acc += __shfl_xor(acc, 8);
    if (part == 0) ws[WS_IOU + row] = acc + b_iou[row];
}

// k4: finalize c and h (sums the 32 c_acc shards).
__global__ __launch_bounds__(512) void k4_fin(const float* __restrict__ ws,
                                              float* __restrict__ out) {
    const int h = threadIdx.x;
    float cacc = 0.0f;
#pragma unroll 8
    for (int s = 0; s < NSHARD; ++s) cacc += ws[WS_CACC + s * H + h];
    const float i = sigm(ws[WS_IOU + h]);
    const float o = sigm(ws[WS_IOU + 512 + h]);
    const float u = tanhf(ws[WS_IOU + 1024 + h]);
    const float c = i * u + cacc;
    out[h]       = o * tanhf(c);
    out[512 + h] = c;
}

extern "C" void kernel_launch(void* const* d_in, const int* in_sizes, int n_in,
                              void* d_out, int out_size, void* d_ws, size_t ws_size,
                              hipStream_t stream) {
    const float* x     = (const float*)d_in[0];
    const float* hs    = (const float*)d_in[1];
    const float* cs    = (const float*)d_in[2];
    const float* w_iou = (const float*)d_in[3];
    const float* u_iou = (const float*)d_in[4];
    const float* b_iou = (const float*)d_in[5];
    const float* w_f   = (const float*)d_in[6];
    const float* u_f   = (const float*)d_in[7];
    const float* b_f   = (const float*)d_in[8];
    float* ws  = (float*)d_ws;
    float* out = (float*)d_out;

    k0_setup<<<264, 256, 0, stream>>>(x, w_f, b_f, u_f, ws);
    k2_main<<<(NCHLD / NB) * 2, 256, 0, stream>>>(hs, cs, ws);
    k3_iou<<<96, 256, 0, stream>>>(x, w_iou, u_iou, b_iou, ws);
    k4_fin<<<1, 512, 0, stream>>>(ws, out);
}

// Round 10
// 229.859 us; speedup vs baseline: 1.0595x; 1.0595x over previous
//
#include <hip/hip_runtime.h>
#include <stdint.h>
#include <stddef.h>

#define H 512
#define XD 256
#define NCHLD 32768
#define NB 32               // children per k2 block
#define NSHARD 32

// ws layout (floats):
#define WS_PREF 0           // [0,512)       pre_f = w_f@x + b_f
#define WS_IOU  512         // [512,2048)    iou logits
#define WS_CACC 2048        // [2048,18432)  32 shards x 512
#define WS_HSUM 18432       // [18432,34816) 32 shards x 512
#define WS_UF16 34816       // u_f as f16: 262144 halves = 131072 float slots

typedef float f32x4 __attribute__((ext_vector_type(4)));
typedef _Float16 f16x8 __attribute__((ext_vector_type(8)));

__device__ __forceinline__ float sigm(float x) { return 1.0f / (1.0f + __expf(-x)); }

__device__ __forceinline__ void gload_lds16(const float* g, void* l) {
    __builtin_amdgcn_global_load_lds((const __attribute__((address_space(1))) void*)g,
                                     (__attribute__((address_space(3))) void*)l,
                                     16, 0, 0);
}

// k0: (a) u_f -> f16 (blocks 0..255); (b) pre_f + zero shard arrays (blocks 256..263).
__global__ __launch_bounds__(256) void k0_setup(const float* __restrict__ x,
                                                const float* __restrict__ w_f,
                                                const float* __restrict__ b_f,
                                                const float* __restrict__ u_f,
                                                float* __restrict__ ws) {
    const int b = blockIdx.x;
    if (b < 256) {
        const int i = (b * 256 + threadIdx.x) * 4;
        float4 v = *(const float4*)(u_f + i);
        _Float16* dst = (_Float16*)(ws + WS_UF16) + i;
        dst[0] = (_Float16)v.x; dst[1] = (_Float16)v.y;
        dst[2] = (_Float16)v.z; dst[3] = (_Float16)v.w;
    } else {
        const int gid = (b - 256) * 256 + threadIdx.x;   // [0,2048)
        const int row = gid >> 2;
        const int part = gid & 3;
        const float4* wr = (const float4*)(w_f + (size_t)row * XD) + part * 16;
        const float4* xv = (const float4*)x + part * 16;
        float acc = 0.0f;
#pragma unroll 4
        for (int i = 0; i < 16; ++i) {
            float4 a = wr[i], c = xv[i];
            acc += a.x * c.x + a.y * c.y + a.z * c.z + a.w * c.w;
        }
        acc += __shfl_xor(acc, 1);
        acc += __shfl_xor(acc, 2);
        if (part == 0) ws[WS_PREF + row] = acc + b_f[row];
        // zero CACC+HSUM = floats [2048, 34816) = float4 idx [512, 8704)
        float4 z = make_float4(0.f, 0.f, 0.f, 0.f);
#pragma unroll
        for (int t = 0; t < 4; ++t)
            ((float4*)ws)[512 + gid * 4 + t] = z;
    }
}

// k2: fs = sigmoid(pre_f + u_f@hs^T) fused with c partials and exact-f32 h_sum.
// hs tile (32 children x 512, f32 = 64 KB) staged via global_load_lds DMA with
// source-side XOR swizzle (16B slots; LDS slot s of row r holds global slot
// s^(r&7), reads apply the same XOR). 512 thr, grid 1024, 2 blocks/CU.
__global__ __launch_bounds__(512, 4) void k2_main(const float* __restrict__ hs,
                                                  const float* __restrict__ cs,
                                                  float* __restrict__ ws) {
    __shared__ float Bs[NB * H];   // 64 KB

    const _Float16* uf16 = (const _Float16*)(ws + WS_UF16);
    const float* pre_f = ws + WS_PREF;
    const int bid = blockIdx.x;
    const int c0  = bid * NB;
    float* c_acc   = ws + WS_CACC + (bid & (NSHARD - 1)) * H;
    float* h_shard = ws + WS_HSUM + (bid & (NSHARD - 1)) * H;

    const int tid  = threadIdx.x;
    const int wid  = tid >> 6;
    const int lane = tid & 63;
    const int fc   = lane & 15;
    const int q    = lane >> 4;

    // ---- DMA staging: wave wid issues 8x 1KB (lane-strided 16B), zero VGPR cost ----
#pragma unroll
    for (int t = 0; t < 8; ++t) {
        const int idx  = wid * 8 + t;        // half-row index [0,64)
        const int r    = idx >> 1;           // child row [0,32)
        const int half = idx & 1;
        const int slot_g = half * 64 + (lane ^ (r & 7));
        gload_lds16(hs + (size_t)(c0 + r) * H + slot_g * 4,
                    (char*)Bs + (size_t)idx * 1024);
    }
    __syncthreads();   // drains DMA (compiler emits vmcnt(0) before barrier)

    // ---- h_sum: thread tid sums column tid over the 32 children (exact f32) ----
    {
        const int sl = tid >> 2, wd = tid & 3;
        float hsum = 0.0f;
#pragma unroll
        for (int ch = 0; ch < NB; ++ch)
            hsum += *(const float*)((const char*)Bs + ch * 2048 + ((sl ^ (ch & 7)) << 4) + wd * 4);
        atomicAdd(&h_shard[tid], hsum);
    }

    // ---- K-loop: wave owns rows [wid*64,+64); A from L2 (f16), B from LDS (f32->f16) ----
    f32x4 acc[4][2];
    const f32x4 vzero = {0.0f, 0.0f, 0.0f, 0.0f};
#pragma unroll
    for (int rt = 0; rt < 4; ++rt) { acc[rt][0] = vzero; acc[rt][1] = vzero; }

    const _Float16* abase = uf16 + (size_t)(wid * 64 + fc) * H + q * 8;

    f16x8 af[4], afn[4];
#pragma unroll
    for (int rt = 0; rt < 4; ++rt)
        af[rt] = *(const f16x8*)(abase + (size_t)rt * 16 * H);

#pragma unroll
    for (int kk = 0; kk < 16; ++kk) {
        if (kk < 15) {
#pragma unroll
            for (int rt = 0; rt < 4; ++rt)
                afn[rt] = *(const f16x8*)(abase + (size_t)rt * 16 * H + (kk + 1) * 32);
        }
        const int s0 = kk * 8 + q * 2;       // even 16B-slot holding k = kk*32+q*8 .. +3
        f16x8 bf[2];
#pragma unroll
        for (int ct = 0; ct < 2; ++ct) {
            const int child = ct * 16 + fc;
            const int sl0 = s0 ^ (fc & 7);   // LDS slot of global slot s0
            f32x4 v0 = *(const f32x4*)((const char*)Bs + child * 2048 + (sl0 << 4));
            f32x4 v1 = *(const f32x4*)((const char*)Bs + child * 2048 + ((sl0 ^ 1) << 4));
            f16x8 bv;
            bv[0] = (_Float16)v0[0]; bv[1] = (_Float16)v0[1];
            bv[2] = (_Float16)v0[2]; bv[3] = (_Float16)v0[3];
            bv[4] = (_Float16)v1[0]; bv[5] = (_Float16)v1[1];
            bv[6] = (_Float16)v1[2]; bv[7] = (_Float16)v1[3];
            bf[ct] = bv;
        }
#pragma unroll
        for (int ct = 0; ct < 2; ++ct)
#pragma unroll
            for (int rt = 0; rt < 4; ++rt)
                acc[rt][ct] = __builtin_amdgcn_mfma_f32_16x16x32_f16(af[rt], bf[ct], acc[rt][ct], 0, 0, 0);
        if (kk < 15) {
#pragma unroll
            for (int rt = 0; rt < 4; ++rt) af[rt] = afn[rt];
        }
    }

    // ---- epilogue: sigmoid, * cs, reduce over 16 children per col-tile ----
#pragma unroll
    for (int rt = 0; rt < 4; ++rt) {
        const int rglob = wid * 64 + rt * 16 + q * 4;
        float4 pf = *(const float4*)(pre_f + rglob);
        f32x4 csum = vzero;
#pragma unroll
        for (int ct = 0; ct < 2; ++ct) {
            const int child = c0 + ct * 16 + fc;
            float4 cv = *(const float4*)(cs + (size_t)child * H + rglob);
            csum[0] += sigm(acc[rt][ct][0] + pf.x) * cv.x;
            csum[1] += sigm(acc[rt][ct][1] + pf.y) * cv.y;
            csum[2] += sigm(acc[rt][ct][2] + pf.z) * cv.z;
            csum[3] += sigm(acc[rt][ct][3] + pf.w) * cv.w;
        }
#pragma unroll
        for (int m = 1; m <= 8; m <<= 1) {
            csum[0] += __shfl_xor(csum[0], m); csum[1] += __shfl_xor(csum[1], m);
            csum[2] += __shfl_xor(csum[2], m); csum[3] += __shfl_xor(csum[3], m);
        }
        if (fc == 0) {
            atomicAdd(&c_acc[rglob + 0], csum[0]); atomicAdd(&c_acc[rglob + 1], csum[1]);
            atomicAdd(&c_acc[rglob + 2], csum[2]); atomicAdd(&c_acc[rglob + 3], csum[3]);
        }
    }
}

// k3: iou logits; reduces the 32 h_sum shards into LDS first. 96 blocks x 256 thr.
__global__ __launch_bounds__(256) void k3_iou(const float* __restrict__ x,
                                              const float* __restrict__ w_iou,
                                              const float* __restrict__ u_iou,
                                              const float* __restrict__ b_iou,
                                              float* __restrict__ ws) {
    __shared__ float h_red[H];
    const int tid = threadIdx.x;
    {
        float a0 = 0.0f, a1 = 0.0f;
#pragma unroll 8
        for (int s = 0; s < NSHARD; ++s) {
            a0 += ws[WS_HSUM + s * H + tid * 2 + 0];
            a1 += ws[WS_HSUM + s * H + tid * 2 + 1];
        }
        h_red[tid * 2 + 0] = a0;
        h_red[tid * 2 + 1] = a1;
    }
    __syncthreads();

    const int gid = blockIdx.x * 256 + tid;   // [0,24576)
    const int row = gid >> 4;                  // [0,1536)
    const int part = gid & 15;
    float acc = 0.0f;
    const float4* wr = (const float4*)(w_iou + (size_t)row * XD) + part * 4;
    const float4* xv = (const float4*)x + part * 4;
#pragma unroll
    for (int i = 0; i < 4; ++i) {
        float4 a = wr[i], b = xv[i];
        acc += a.x * b.x + a.y * b.y + a.z * b.z + a.w * b.w;
    }
    const float4* ur = (const float4*)(u_iou + (size_t)row * H) + part * 8;
    const float4* hv = (const float4*)h_red + part * 8;
#pragma unroll
    for (int i = 0; i < 8; ++i) {
        float4 a = ur[i], b = hv[i];
        acc += a.x * b.x + a.y * b.y + a.z * b.z + a.w * b.w;
    }
    acc += __shfl_xor(acc, 1);
    acc += __shfl_xor(acc, 2);
    acc += __shfl_xor(acc, 4);
    acc += __shfl_xor(acc, 8);
    if (part == 0) ws[WS_IOU + row] = acc + b_iou[row];
}

// k4: finalize c and h (sums the 32 c_acc shards).
__global__ __launch_bounds__(512) void k4_fin(const float* __restrict__ ws,
                                              float* __restrict__ out) {
    const int h = threadIdx.x;
    float cacc = 0.0f;
#pragma unroll 8
    for (int s = 0; s < NSHARD; ++s) cacc += ws[WS_CACC + s * H + h];
    const float i = sigm(ws[WS_IOU + h]);
    const float o = sigm(ws[WS_IOU + 512 + h]);
    const float u = tanhf(ws[WS_IOU + 1024 + h]);
    const float c = i * u + cacc;
    out[h]       = o * tanhf(c);
    out[512 + h] = c;
}

extern "C" void kernel_launch(void* const* d_in, const int* in_sizes, int n_in,
                              void* d_out, int out_size, void* d_ws, size_t ws_size,
                              hipStream_t stream) {
    const float* x     = (const float*)d_in[0];
    const float* hs    = (const float*)d_in[1];
    const float* cs    = (const float*)d_in[2];
    const float* w_iou = (const float*)d_in[3];
    const float* u_iou = (const float*)d_in[4];
    const float* b_iou = (const float*)d_in[5];
    const float* w_f   = (const float*)d_in[6];
    const float* u_f   = (const float*)d_in[7];
    const float* b_f   = (const float*)d_in[8];
    float* ws  = (float*)d_ws;
    float* out = (float*)d_out;

    k0_setup<<<264, 256, 0, stream>>>(x, w_f, b_f, u_f, ws);
    k2_main<<<NCHLD / NB, 512, 0, stream>>>(hs, cs, ws);
    k3_iou<<<96, 256, 0, stream>>>(x, w_iou, u_iou, b_iou, ws);
    k4_fin<<<1, 512, 0, stream>>>(ws, out);
}